// Round 5
// baseline (14639.590 us; speedup 1.0000x reference)
//
#include <hip/hip_runtime.h>
#include <hip/hip_bf16.h>

// RK4 latent ODE: f(y) = tanh(y@W1+b1)@W2 + b2. B=1024, D=512, H=1024, T=64.
// R5 KEY FIX: d_out is FLOAT32 (reference output dtype), not bf16.
// Evidence: R2/R3/R4 bit-identical absmax 7.9375 across different MFMA
// precisions + layout probe => error independent of math => output dtype.
// Writing bf16 into an fp32 buffer => harness reads pairs as floats (~7.9 max
// vs 5.47 for all-zero) - matches measured values exactly.
// Inputs: runtime dtype detect on ts (fp32 vs bf16); role mapping from
// in_sizes (elements or bytes; dict or alphabetical order; dict fallback).
// Structure (unchanged, believed correct since R2): one kernel runs all 63
// steps; 64 blocks x 16 batch rows; state in registers (MFMA C/D layout);
// fp16 activations staged in LDS; fp16 transposed weights (2 MB d_ws) from L2.

#define B_ 1024
#define D_ 512
#define H_ 1024
#define T_ 64
#define M_ 16   // batch rows per block

typedef unsigned short ushort_t;
typedef _Float16 f16x8 __attribute__((ext_vector_type(8)));
typedef float f32x4 __attribute__((ext_vector_type(4)));
typedef unsigned short ushortx8 __attribute__((ext_vector_type(8)));

__device__ __forceinline__ float bf2f(ushort_t u) {
  union { unsigned u; float f; } v;
  v.u = ((unsigned)u) << 16;
  return v.f;
}

__device__ __forceinline__ ushort_t f2h(float f) {
  return __builtin_bit_cast(ushort_t, (_Float16)f);   // RNE fp16
}

// dual-dtype scalar read: fp32 or bf16 element i
__device__ __forceinline__ float ldf(const void* p, int i, bool f32) {
  return f32 ? ((const float*)p)[i] : bf2f(((const ushort_t*)p)[i]);
}

__device__ __forceinline__ bool is_f32_inputs(const void* ts) {
  // fp32: ts[0]=0.0f -> ushort[1] (high half) == 0; bf16: ts[1]=bf16(1/63)!=0
  return ((const ushort_t*)ts)[1] == 0;
}

__device__ __forceinline__ float tanh_fast(float x) {
  float e = __builtin_amdgcn_exp2f(x * 2.885390081777927f);  // exp(2x)
  return 1.0f - 2.0f * __builtin_amdgcn_rcpf(e + 1.0f);      // NaN-free
}

__device__ __forceinline__ f16x8 ld8(const ushort_t* p) {
  return __builtin_bit_cast(f16x8, *(const ushortx8*)p);
}

__device__ __forceinline__ f32x4 mfma16f(f16x8 a, f16x8 b, f32x4 c) {
  return __builtin_amdgcn_mfma_f32_16x16x32_f16(a, b, c, 0, 0, 0);
}

// ---- prep: transpose + convert weights: in [R][C] (fp32/bf16) -> out [C][R] fp16 ----
__global__ void transpose_conv(const void* __restrict__ in, ushort_t* __restrict__ out,
                               int R, int C, const void* __restrict__ ts) {
  const bool f32 = is_f32_inputs(ts);
  __shared__ ushort_t tile[32][33];
  const int bc = blockIdx.x * 32;           // col base (input)
  const int br = blockIdx.y * 32;           // row base (input)
  const int tx = threadIdx.x & 31;
  const int ty = threadIdx.x >> 5;          // 0..7
#pragma unroll
  for (int i = 0; i < 32; i += 8) {
    const size_t idx = (size_t)(br + ty + i) * C + bc + tx;
    const float v = f32 ? ((const float*)in)[idx] : bf2f(((const ushort_t*)in)[idx]);
    tile[ty + i][tx] = f2h(v);
  }
  __syncthreads();
#pragma unroll
  for (int i = 0; i < 32; i += 8)
    out[(size_t)(bc + ty + i) * R + br + tx] = tile[tx][ty + i];
}

// ---- main trajectory kernel ----
// Per wave w (of 4), lane l: m = l&15, quad = l>>4.
// A map: A[m][quad*8+j]; B map: B[quad*8+j][m]; C/D: row=quad*4+r, col=m.
// GEMM1: wave owns h cols [w*256, w*256+256): 16 tiles, K=512
// GEMM2: wave owns k cols [w*128, w*128+128):  8 tiles, K=1024
__global__ __launch_bounds__(256, 1)
void rk4_kernel(const void* __restrict__ y0,     // [B][D]
                const void* __restrict__ ts,     // [T]
                const ushort_t* __restrict__ w1t,// [H][D] fp16 (W1^T)
                const void* __restrict__ b1,     // [H]
                const ushort_t* __restrict__ w2t,// [D][H] fp16 (W2^T)
                const void* __restrict__ b2,     // [D]
                float* __restrict__ out)         // [T][B][D] FP32
{
  __shared__ __align__(16) ushort_t yS[M_][D_ + 8];   // fp16 yin, ~16.6 KB
  __shared__ __align__(16) ushort_t hS[M_][H_ + 8];   // fp16 h,   ~33.0 KB

  const bool f32i = is_f32_inputs(ts);
  const int tid  = threadIdx.x;
  const int wave = tid >> 6;
  const int lane = tid & 63;
  const int m    = lane & 15;
  const int quad = lane >> 4;
  const int rowbase = blockIdx.x * M_;
  const int cw1 = wave * 256;   // GEMM1 output col base (H index)
  const int cw2 = wave * 128;   // GEMM2 output col base (D index)

  float b1v[16], b2v[8];
#pragma unroll
  for (int n = 0; n < 16; n++) b1v[n] = ldf(b1, cw1 + n * 16 + m, f32i);
#pragma unroll
  for (int n = 0; n < 8; n++)  b2v[n] = ldf(b2, cw2 + n * 16 + m, f32i);

  // state: element (n,r) <-> global row rowbase+quad*4+r, col cw2+n*16+m
  float y[8][4], acc[8][4], k[8][4];
#pragma unroll
  for (int n = 0; n < 8; n++)
#pragma unroll
    for (int r = 0; r < 4; r++) {
      const int row = rowbase + quad * 4 + r;
      const int col = cw2 + n * 16 + m;
      y[n][r] = ldf(y0, row * D_ + col, f32i);
      out[(size_t)row * D_ + col] = y[n][r];   // t=0 plane, fp32
      k[n][r] = 0.0f;
      acc[n][r] = 0.0f;
    }

#pragma unroll 1
  for (int step = 0; step < T_ - 1; step++) {
    const float dt = ldf(ts, step + 1, f32i) - ldf(ts, step, f32i);

#pragma unroll 1
    for (int e = 0; e < 4; e++) {
      const float c = (e == 0) ? 0.0f : ((e == 3) ? dt : 0.5f * dt);
      const float w = ((e == 1) || (e == 2)) ? 2.0f : 1.0f;

      // ---- stage yin = y + c*k into LDS (fp16) ----
#pragma unroll
      for (int n = 0; n < 8; n++)
#pragma unroll
        for (int r = 0; r < 4; r++)
          yS[quad * 4 + r][cw2 + n * 16 + m] = f2h(y[n][r] + c * k[n][r]);
      __syncthreads();

      // ---- GEMM1: h = yin @ W1 (wave: 16 col-tiles, K=512) ----
      f32x4 hacc[16];
#pragma unroll
      for (int n = 0; n < 16; n++) hacc[n] = (f32x4){0.f, 0.f, 0.f, 0.f};
#pragma unroll 1
      for (int k0 = 0; k0 < D_; k0 += 32) {
        const f16x8 a = ld8(&yS[m][k0 + quad * 8]);
        const ushort_t* bp = w1t + (size_t)(cw1 + m) * D_ + k0 + quad * 8;
#pragma unroll
        for (int n = 0; n < 16; n++) {
          const f16x8 b = ld8(bp + (size_t)n * 16 * D_);
          hacc[n] = mfma16f(a, b, hacc[n]);
        }
      }

      // ---- bias + tanh -> hS (fp16) ----
#pragma unroll
      for (int n = 0; n < 16; n++)
#pragma unroll
        for (int r = 0; r < 4; r++)
          hS[quad * 4 + r][cw1 + n * 16 + m] = f2h(tanh_fast(hacc[n][r] + b1v[n]));
      __syncthreads();

      // ---- GEMM2: k = h @ W2 + b2 (wave: 8 col-tiles, K=1024) ----
      f32x4 kacc[8];
#pragma unroll
      for (int n = 0; n < 8; n++) kacc[n] = (f32x4){0.f, 0.f, 0.f, 0.f};
#pragma unroll 2
      for (int k0 = 0; k0 < H_; k0 += 32) {
        const f16x8 a = ld8(&hS[m][k0 + quad * 8]);
        const ushort_t* bp = w2t + (size_t)(cw2 + m) * H_ + k0 + quad * 8;
#pragma unroll
        for (int n = 0; n < 8; n++) {
          const f16x8 b = ld8(bp + (size_t)n * 16 * H_);
          kacc[n] = mfma16f(a, b, kacc[n]);
        }
      }

#pragma unroll
      for (int n = 0; n < 8; n++)
#pragma unroll
        for (int r = 0; r < 4; r++) {
          k[n][r] = kacc[n][r] + b2v[n];
          if (e == 0) acc[n][r] = k[n][r];
          else        acc[n][r] += w * k[n][r];
        }
    }

    // ---- y update + fp32 output store ----
    float* op = out + (size_t)(step + 1) * B_ * D_;
    const float s = dt * (1.0f / 6.0f);
#pragma unroll
    for (int n = 0; n < 8; n++)
#pragma unroll
      for (int r = 0; r < 4; r++) {
        y[n][r] += s * acc[n][r];
        op[(size_t)(rowbase + quad * 4 + r) * D_ + cw2 + n * 16 + m] = y[n][r];
      }
  }
}

extern "C" void kernel_launch(void* const* d_in, const int* in_sizes, int n_in,
                              void* d_out, int out_size, void* d_ws, size_t ws_size,
                              hipStream_t stream) {
  // ---- role mapping from in_sizes: tolerate elements-or-bytes, dict-or-alpha ----
  // elements: fp=524288, ts=64, W1=524288, b1=1024, W2=524288, b2=512
  int iTs = -1, sc = 1;
  for (int i = 0; i < n_in; i++)
    if (in_sizes[i] == 64 || in_sizes[i] == 128 || in_sizes[i] == 256) {
      iTs = i; sc = in_sizes[i] / 64; break;   // sc: 1=elem, 2=bytes bf16, 4=bytes fp32
    }
  if (iTs < 0) { iTs = 1; sc = 1; }
  int iB1 = -1, iB2 = -1, bigs[3]; int nb = 0;
  for (int i = 0; i < n_in; i++) {
    if (i == iTs) continue;
    if (in_sizes[i] == 1024 * sc) iB1 = i;
    else if (in_sizes[i] == 512 * sc) iB2 = i;
    else if (nb < 3) bigs[nb++] = i;
  }
  if (iB1 < 0) iB1 = 3;
  if (iB2 < 0) iB2 = 5;
  if (nb < 3) { bigs[0] = 0; bigs[1] = 2; bigs[2] = 4; }
  const void *y0, *w1, *w2;
  if (iTs == 1) {            // dict order: first_point, ts, W1, b1, W2, b2
    y0 = d_in[bigs[0]]; w1 = d_in[bigs[1]]; w2 = d_in[bigs[2]];
  } else {                   // alphabetical: W1, W2, b1, b2, first_point, ts
    w1 = d_in[bigs[0]]; w2 = d_in[bigs[1]]; y0 = d_in[bigs[2]];
  }
  const void* ts = d_in[iTs];
  const void* b1 = d_in[iB1];
  const void* b2 = d_in[iB2];
  float* out = (float*)d_out;   // FP32 output (reference dtype)

  // ws: w1t fp16 [H][D] (1 MB) | w2t fp16 [D][H] (1 MB)
  ushort_t* w1t = (ushort_t*)d_ws;
  ushort_t* w2t = w1t + (size_t)D_ * H_;

  dim3 tb(256);
  // W1 [512][1024] -> W1T [1024][512]
  transpose_conv<<<dim3(H_ / 32, D_ / 32), tb, 0, stream>>>(w1, w1t, D_, H_, ts);
  // W2 [1024][512] -> W2T [512][1024]
  transpose_conv<<<dim3(D_ / 32, H_ / 32), tb, 0, stream>>>(w2, w2t, H_, D_, ts);

  rk4_kernel<<<dim3(B_ / M_), tb, 0, stream>>>(y0, ts, w1t, b1, w2t, b2, out);
}

// Round 6
// 14260.562 us; speedup vs baseline: 1.0266x; 1.0266x over previous
//
#include <hip/hip_runtime.h>
#include <hip/hip_bf16.h>

// RK4 latent ODE: f(y) = tanh(y@W1+b1)@W2 + b2. B=1024, D=512, H=1024, T=64.
// R5 passed (absmax 0.031) at 14.6 ms: Occupancy 3.1% = 1 wave/CU -> pure
// latency bound. R6: 1024-thread blocks (16 waves) -> 4 waves/SIMD TLP,
// depth-1 register prefetch of weight fragments + LDS A-reads, GEMM2 k-loop
// unrolled x2. Same proven numerics/mapping as R5 (fp32 out, in_sizes role
// mapping, runtime dtype detect, fp16 weights/activations, fp32 state).

#define B_ 1024
#define D_ 512
#define H_ 1024
#define T_ 64
#define M_ 16   // batch rows per block
#define NW 16   // waves per block

typedef unsigned short ushort_t;
typedef _Float16 f16x8 __attribute__((ext_vector_type(8)));
typedef float f32x4 __attribute__((ext_vector_type(4)));
typedef unsigned short ushortx8 __attribute__((ext_vector_type(8)));

__device__ __forceinline__ float bf2f(ushort_t u) {
  union { unsigned u; float f; } v;
  v.u = ((unsigned)u) << 16;
  return v.f;
}

__device__ __forceinline__ ushort_t f2h(float f) {
  return __builtin_bit_cast(ushort_t, (_Float16)f);   // RNE fp16
}

// dual-dtype scalar read: fp32 or bf16 element i
__device__ __forceinline__ float ldf(const void* p, int i, bool f32) {
  return f32 ? ((const float*)p)[i] : bf2f(((const ushort_t*)p)[i]);
}

__device__ __forceinline__ bool is_f32_inputs(const void* ts) {
  // fp32: ts[0]=0.0f -> ushort[1] (high half) == 0; bf16: ts[1]=bf16(1/63)!=0
  return ((const ushort_t*)ts)[1] == 0;
}

__device__ __forceinline__ float tanh_fast(float x) {
  float e = __builtin_amdgcn_exp2f(x * 2.885390081777927f);  // exp(2x)
  return 1.0f - 2.0f * __builtin_amdgcn_rcpf(e + 1.0f);      // NaN-free
}

__device__ __forceinline__ f16x8 ld8(const ushort_t* p) {
  return __builtin_bit_cast(f16x8, *(const ushortx8*)p);
}

__device__ __forceinline__ f32x4 mfma16f(f16x8 a, f16x8 b, f32x4 c) {
  return __builtin_amdgcn_mfma_f32_16x16x32_f16(a, b, c, 0, 0, 0);
}

// ---- prep: transpose + convert weights: in [R][C] (fp32/bf16) -> out [C][R] fp16 ----
__global__ void transpose_conv(const void* __restrict__ in, ushort_t* __restrict__ out,
                               int R, int C, const void* __restrict__ ts) {
  const bool f32 = is_f32_inputs(ts);
  __shared__ ushort_t tile[32][33];
  const int bc = blockIdx.x * 32;
  const int br = blockIdx.y * 32;
  const int tx = threadIdx.x & 31;
  const int ty = threadIdx.x >> 5;          // 0..7
#pragma unroll
  for (int i = 0; i < 32; i += 8) {
    const size_t idx = (size_t)(br + ty + i) * C + bc + tx;
    const float v = f32 ? ((const float*)in)[idx] : bf2f(((const ushort_t*)in)[idx]);
    tile[ty + i][tx] = f2h(v);
  }
  __syncthreads();
#pragma unroll
  for (int i = 0; i < 32; i += 8)
    out[(size_t)(bc + ty + i) * R + br + tx] = tile[tx][ty + i];
}

// ---- main trajectory kernel: 64 blocks x 1024 threads (16 waves) ----
// Per wave w (0..15), lane l: m=l&15, quad=l>>4.
// A map: A[m][quad*8+j]; B map: B[quad*8+j][col]; C/D: row=quad*4+r, col=m.
// GEMM1: wave owns h cols [w*64, w*64+64):   4 tiles, K=512  (16 iters)
// GEMM2: wave owns k cols [w*32, w*32+32):   2 tiles, K=1024 (16 iters, x2 unroll)
__global__ __launch_bounds__(1024, 4)
void rk4_kernel(const void* __restrict__ y0,     // [B][D]
                const void* __restrict__ ts,     // [T]
                const ushort_t* __restrict__ w1t,// [H][D] fp16 (W1^T)
                const void* __restrict__ b1,     // [H]
                const ushort_t* __restrict__ w2t,// [D][H] fp16 (W2^T)
                const void* __restrict__ b2,     // [D]
                float* __restrict__ out)         // [T][B][D] fp32
{
  __shared__ __align__(16) ushort_t yS[M_][D_ + 8];   // fp16 yin
  __shared__ __align__(16) ushort_t hS[M_][H_ + 8];   // fp16 h

  const bool f32i = is_f32_inputs(ts);
  const int tid  = threadIdx.x;
  const int wave = tid >> 6;
  const int lane = tid & 63;
  const int m    = lane & 15;
  const int quad = lane >> 4;
  const int rowbase = blockIdx.x * M_;
  const int cw1 = wave * 64;    // GEMM1 output col base (H index)
  const int cw2 = wave * 32;    // GEMM2 output col base (D index)

  float b1v[4], b2v[2];
#pragma unroll
  for (int n = 0; n < 4; n++) b1v[n] = ldf(b1, cw1 + n * 16 + m, f32i);
#pragma unroll
  for (int n = 0; n < 2; n++) b2v[n] = ldf(b2, cw2 + n * 16 + m, f32i);

  // weight fragment base pointers (advance by imm k-offsets inside loops)
  const ushort_t* p1[4];
#pragma unroll
  for (int n = 0; n < 4; n++) p1[n] = w1t + (size_t)(cw1 + n * 16 + m) * D_ + quad * 8;
  const ushort_t* p2[2];
#pragma unroll
  for (int n = 0; n < 2; n++) p2[n] = w2t + (size_t)(cw2 + n * 16 + m) * H_ + quad * 8;

  // state: element (n,r) <-> global row rowbase+quad*4+r, col cw2+n*16+m
  float y[2][4], acc[2][4], k[2][4];
#pragma unroll
  for (int n = 0; n < 2; n++)
#pragma unroll
    for (int r = 0; r < 4; r++) {
      const int row = rowbase + quad * 4 + r;
      const int col = cw2 + n * 16 + m;
      y[n][r] = ldf(y0, row * D_ + col, f32i);
      out[(size_t)row * D_ + col] = y[n][r];   // t=0 plane
      k[n][r] = 0.0f;
      acc[n][r] = 0.0f;
    }

#pragma unroll 1
  for (int step = 0; step < T_ - 1; step++) {
    const float dt = ldf(ts, step + 1, f32i) - ldf(ts, step, f32i);

#pragma unroll 1
    for (int e = 0; e < 4; e++) {
      const float c = (e == 0) ? 0.0f : ((e == 3) ? dt : 0.5f * dt);
      const float w = ((e == 1) || (e == 2)) ? 2.0f : 1.0f;

      // ---- stage yin = y + c*k into LDS (fp16) ----
#pragma unroll
      for (int n = 0; n < 2; n++)
#pragma unroll
        for (int r = 0; r < 4; r++)
          yS[quad * 4 + r][cw2 + n * 16 + m] = f2h(y[n][r] + c * k[n][r]);
      __syncthreads();

      // ---- GEMM1: h = yin @ W1 (4 tiles, 16 K-iters, depth-1 prefetch) ----
      f32x4 hacc[4];
#pragma unroll
      for (int n = 0; n < 4; n++) hacc[n] = (f32x4){0.f, 0.f, 0.f, 0.f};
      f16x8 a0 = ld8(&yS[m][quad * 8]);
      f16x8 bb[4];
#pragma unroll
      for (int n = 0; n < 4; n++) bb[n] = ld8(p1[n]);
#pragma unroll 1
      for (int k0 = 0; k0 < D_; k0 += 32) {
        const int kn = (k0 + 32 < D_) ? (k0 + 32) : 0;   // dummy wrap prefetch
        f16x8 a1 = ld8(&yS[m][kn + quad * 8]);
        f16x8 bn[4];
#pragma unroll
        for (int n = 0; n < 4; n++) bn[n] = ld8(p1[n] + kn);
#pragma unroll
        for (int n = 0; n < 4; n++) hacc[n] = mfma16f(a0, bb[n], hacc[n]);
        a0 = a1;
#pragma unroll
        for (int n = 0; n < 4; n++) bb[n] = bn[n];
      }

      // ---- bias + tanh -> hS (fp16) ----
#pragma unroll
      for (int n = 0; n < 4; n++)
#pragma unroll
        for (int r = 0; r < 4; r++)
          hS[quad * 4 + r][cw1 + n * 16 + m] = f2h(tanh_fast(hacc[n][r] + b1v[n]));
      __syncthreads();

      // ---- GEMM2: k = h @ W2 + b2 (2 tiles, K=1024, x2-unrolled, prefetch) ----
      f32x4 kacc[2];
#pragma unroll
      for (int n = 0; n < 2; n++) kacc[n] = (f32x4){0.f, 0.f, 0.f, 0.f};
      f16x8 c0 = ld8(&hS[m][quad * 8]);
      f16x8 c1 = ld8(&hS[m][32 + quad * 8]);
      f16x8 db[4];   // [n][half]: n*2+half
#pragma unroll
      for (int n = 0; n < 2; n++) {
        db[n * 2]     = ld8(p2[n]);
        db[n * 2 + 1] = ld8(p2[n] + 32);
      }
#pragma unroll 1
      for (int k0 = 0; k0 < H_; k0 += 64) {
        const int kn = (k0 + 64 < H_) ? (k0 + 64) : 0;   // dummy wrap prefetch
        f16x8 a1 = ld8(&hS[m][kn + quad * 8]);
        f16x8 a2 = ld8(&hS[m][kn + 32 + quad * 8]);
        f16x8 dn[4];
#pragma unroll
        for (int n = 0; n < 2; n++) {
          dn[n * 2]     = ld8(p2[n] + kn);
          dn[n * 2 + 1] = ld8(p2[n] + kn + 32);
        }
#pragma unroll
        for (int n = 0; n < 2; n++) {
          kacc[n] = mfma16f(c0, db[n * 2], kacc[n]);
          kacc[n] = mfma16f(c1, db[n * 2 + 1], kacc[n]);
        }
        c0 = a1; c1 = a2;
#pragma unroll
        for (int n = 0; n < 4; n++) db[n] = dn[n];
      }

#pragma unroll
      for (int n = 0; n < 2; n++)
#pragma unroll
        for (int r = 0; r < 4; r++) {
          k[n][r] = kacc[n][r] + b2v[n];
          if (e == 0) acc[n][r] = k[n][r];
          else        acc[n][r] += w * k[n][r];
        }
    }

    // ---- y update + fp32 output store ----
    float* op = out + (size_t)(step + 1) * B_ * D_;
    const float s = dt * (1.0f / 6.0f);
#pragma unroll
    for (int n = 0; n < 2; n++)
#pragma unroll
      for (int r = 0; r < 4; r++) {
        y[n][r] += s * acc[n][r];
        op[(size_t)(rowbase + quad * 4 + r) * D_ + cw2 + n * 16 + m] = y[n][r];
      }
  }
}

extern "C" void kernel_launch(void* const* d_in, const int* in_sizes, int n_in,
                              void* d_out, int out_size, void* d_ws, size_t ws_size,
                              hipStream_t stream) {
  // ---- role mapping from in_sizes (proven R5): elements-or-bytes, dict-or-alpha ----
  int iTs = -1, sc = 1;
  for (int i = 0; i < n_in; i++)
    if (in_sizes[i] == 64 || in_sizes[i] == 128 || in_sizes[i] == 256) {
      iTs = i; sc = in_sizes[i] / 64; break;
    }
  if (iTs < 0) { iTs = 1; sc = 1; }
  int iB1 = -1, iB2 = -1, bigs[3]; int nb = 0;
  for (int i = 0; i < n_in; i++) {
    if (i == iTs) continue;
    if (in_sizes[i] == 1024 * sc) iB1 = i;
    else if (in_sizes[i] == 512 * sc) iB2 = i;
    else if (nb < 3) bigs[nb++] = i;
  }
  if (iB1 < 0) iB1 = 3;
  if (iB2 < 0) iB2 = 5;
  if (nb < 3) { bigs[0] = 0; bigs[1] = 2; bigs[2] = 4; }
  const void *y0, *w1, *w2;
  if (iTs == 1) {            // dict order: first_point, ts, W1, b1, W2, b2
    y0 = d_in[bigs[0]]; w1 = d_in[bigs[1]]; w2 = d_in[bigs[2]];
  } else {                   // alphabetical: W1, W2, b1, b2, first_point, ts
    w1 = d_in[bigs[0]]; w2 = d_in[bigs[1]]; y0 = d_in[bigs[2]];
  }
  const void* ts = d_in[iTs];
  const void* b1 = d_in[iB1];
  const void* b2 = d_in[iB2];
  float* out = (float*)d_out;

  // ws: w1t fp16 [H][D] (1 MB) | w2t fp16 [D][H] (1 MB)
  ushort_t* w1t = (ushort_t*)d_ws;
  ushort_t* w2t = w1t + (size_t)D_ * H_;

  // W1 [512][1024] -> W1T [1024][512]
  transpose_conv<<<dim3(H_ / 32, D_ / 32), dim3(256), 0, stream>>>(w1, w1t, D_, H_, ts);
  // W2 [1024][512] -> W2T [512][1024]
  transpose_conv<<<dim3(D_ / 32, H_ / 32), dim3(256), 0, stream>>>(w2, w2t, H_, D_, ts);

  rk4_kernel<<<dim3(B_ / M_), dim3(1024), 0, stream>>>(y0, ts, w1t, b1, w2t, b2, out);
}